// Round 4
// baseline (28835.324 us; speedup 1.0000x reference)
//
#include <hip/hip_runtime.h>
#include <stdint.h>

// SimpleGRU  B=64 S=2048 I=256 H=512 O=10
//
// Phase A (proj_mfma): xp2[g][s][1536][16] (bf16) = x@[Wz|Wr|Wh]^T + (b+c), bf16 MFMA GEMM.
// Phase B (gru_recur): persistent 64 blocks = 4 groups(16 batches) x 16 col-slices(32 cols).
//   U weight-stationary in VGPRs.
//   R8: EPOCH-IN-DATA exchange. Every exchanged 64-bit word = {2x bf16 data, uint32 epoch}.
//   Consumers stage+validate in one pass (load 4096 words, write data halves to LDS, accept
//   iff all epochs == expected, retry otherwise). No producer vmcnt drain, no flag store, no
//   poll round-trip: the data IS the flag (8B naturally-aligned loads are atomic).
//   Parity double-buffering (h(t)->hb[t&1], rh(t)->rb[t&1]) makes overwrite safe: writing
//   epoch-t requires having staged epoch-(t-1) from ALL blocks, so readers of t-2 are done.
//   h(-1)=0 epoch 0 comes free from the launch memset. Old flag path kept ONLY as one-shot
//   end-of-kernel barrier before the final projection.
//   (R7 kept: interleaved staging -> bank-uniform LDS writes, coalesced 512B global segments.)

#define S_LEN  2048
#define BATCH  64
#define IDIM   256
#define HDIM   512
#define ODIM   10
#define GATES3 1536

typedef __attribute__((ext_vector_type(8))) short bf16x8;
typedef __attribute__((ext_vector_type(4))) float f32x4;

__device__ __forceinline__ unsigned short f2bf(float x) {
    unsigned int u = __float_as_uint(x);
    u += 0x7fffu + ((u >> 16) & 1u);      // RNE
    return (unsigned short)(u >> 16);
}
__device__ __forceinline__ float bf2f(unsigned short h) {
    return __uint_as_float(((unsigned int)h) << 16);
}

// Cache-bypassing device-coherent accesses (relaxed agent atomics -> sc0 sc1 global ops).
__device__ __forceinline__ unsigned long long g_load64(const void* p) {
    return __hip_atomic_load((const unsigned long long*)p, __ATOMIC_RELAXED, __HIP_MEMORY_SCOPE_AGENT);
}
__device__ __forceinline__ void g_store64(void* p, unsigned long long v) {
    __hip_atomic_store((unsigned long long*)p, v, __ATOMIC_RELAXED, __HIP_MEMORY_SCOPE_AGENT);
}
__device__ __forceinline__ void g_store32(void* p, unsigned int v) {
    __hip_atomic_store((unsigned int*)p, v, __ATOMIC_RELAXED, __HIP_MEMORY_SCOPE_AGENT);
}
__device__ __forceinline__ unsigned int g_load32(const void* p) {
    return __hip_atomic_load((const unsigned int*)p, __ATOMIC_RELAXED, __HIP_MEMORY_SCOPE_AGENT);
}

// ---------------------------------------------------------------------------
// Phase A: bf16 MFMA GEMM. Tile 128(m) x 128(n), K-panels of 64, frag-major LDS.
// m = s*64 + b. grid(12 n-tiles, 1024 m-tiles), 256 threads.  (unchanged, proven)
// ---------------------------------------------------------------------------
__global__ __launch_bounds__(256)
void proj_mfma(const float* __restrict__ x,
               const float* __restrict__ Wz, const float* __restrict__ Wr, const float* __restrict__ Wh,
               const float* __restrict__ bz, const float* __restrict__ cz,
               const float* __restrict__ br, const float* __restrict__ cr,
               const float* __restrict__ bh, const float* __restrict__ ch,
               unsigned short* __restrict__ xp2)
{
    __shared__ unsigned short As[8 * 128 * 8];   // [kcq][row][e]  16 KB
    __shared__ unsigned short Bs[8 * 128 * 8];   // 16 KB
    const int tid  = threadIdx.x;
    const int wave = tid >> 6;
    const int lane = tid & 63;
    const int quad = lane >> 4;
    const int l16  = lane & 15;
    const int nt_ = blockIdx.x;   // 0..11
    const int mt_ = blockIdx.y;   // 0..1023

    const int srow  = tid >> 1;
    const int shalf = tid & 1;
    const int mg = mt_ * 128 + srow;
    const float* axrow = x + ((size_t)(mg & 63) * S_LEN + (mg >> 6)) * IDIM + shalf * 32;
    const int ng = nt_ * 128 + srow;
    const int gt = ng >> 9, hl = ng & 511;
    const float* bxrow = (gt == 0 ? Wz : gt == 1 ? Wr : Wh) + (size_t)hl * IDIM + shalf * 32;

    f32x4 acc[2][8];
#pragma unroll
    for (int mi = 0; mi < 2; ++mi)
#pragma unroll
        for (int nj = 0; nj < 8; ++nj) {
            f32x4 z = {0.f, 0.f, 0.f, 0.f};
            acc[mi][nj] = z;
        }

    for (int kp = 0; kp < IDIM; kp += 64) {
#pragma unroll
        for (int c = 0; c < 4; ++c) {   // kcq = shalf*4 + c
            unsigned short ta[8], tb[8];
#pragma unroll
            for (int e = 0; e < 8; ++e) {
                ta[e] = f2bf(axrow[kp + c * 8 + e]);
                tb[e] = f2bf(bxrow[kp + c * 8 + e]);
            }
            const int kcq = shalf * 4 + c;
            *(bf16x8*)(As + (kcq * 128 + srow) * 8) = *(bf16x8*)ta;
            *(bf16x8*)(Bs + (kcq * 128 + srow) * 8) = *(bf16x8*)tb;
        }
        __syncthreads();
#pragma unroll
        for (int kc = 0; kc < 2; ++kc) {
            bf16x8 af[2], bfr[8];
#pragma unroll
            for (int mi = 0; mi < 2; ++mi)
                af[mi] = *(const bf16x8*)(As + ((kc * 4 + quad) * 128 + wave * 32 + mi * 16 + l16) * 8);
#pragma unroll
            for (int nj = 0; nj < 8; ++nj)
                bfr[nj] = *(const bf16x8*)(Bs + ((kc * 4 + quad) * 128 + nj * 16 + l16) * 8);
#pragma unroll
            for (int mi = 0; mi < 2; ++mi)
#pragma unroll
                for (int nj = 0; nj < 8; ++nj)
                    acc[mi][nj] = __builtin_amdgcn_mfma_f32_16x16x32_bf16(af[mi], bfr[nj], acc[mi][nj], 0, 0, 0);
        }
        __syncthreads();
    }

    const int s_ = mt_ * 2 + (wave >> 1);
#pragma unroll
    for (int nj = 0; nj < 8; ++nj) {
        const int n  = nt_ * 128 + nj * 16 + l16;
        const int g2 = n >> 9, h2 = n & 511;
        const float bias = (g2 == 0 ? bz[h2] + cz[h2]
                          : g2 == 1 ? br[h2] + cr[h2]
                                    : bh[h2] + ch[h2]);
#pragma unroll
        for (int mi = 0; mi < 2; ++mi) {
            const int gg = (wave & 1) * 2 + mi;
            unsigned short pk[4];
#pragma unroll
            for (int r = 0; r < 4; ++r) pk[r] = f2bf(acc[mi][nj][r] + bias);
            *(unsigned long long*)(xp2 + (((size_t)gg * S_LEN + s_) * GATES3 + n) * 16 + quad * 4) =
                *(unsigned long long*)pk;
        }
    }
}

// ---------------------------------------------------------------------------
// Epoch-word channel. Per (parity, group): 4096 x u64 {lo: bf16 pair, hi: epoch}.
// Word index W(row, colpair) = (col>>5)*256 + ((col>>3)&3)*64 + row*4 + ((col&7)>>1)
// == elem_index/2 of the frag-major bf16 layout, so stripping epochs into lds32[W]
// reproduces the exact LDS image the MFMA A-reads expect.
// Stage: thread t owns W = t + i*256 (contiguous 512-B global segments per wave
// instruction; LDS write banks = t%32, 2-way = free). Retry until ALL epochs match.
// ---------------------------------------------------------------------------
__device__ __forceinline__ void stage_epoch(const unsigned long long* __restrict__ src,
                                            unsigned int* __restrict__ lds32, int tid,
                                            unsigned int expect)
{
    for (;;) {
        int ok = 1;
#pragma unroll
        for (int i = 0; i < 16; ++i) {
            const unsigned long long v = g_load64(src + tid + i * 256);
            lds32[tid + i * 256] = (unsigned int)v;
            ok &= ((unsigned int)(v >> 32) == expect) ? 1 : 0;
        }
        if (__syncthreads_and(ok)) break;   // barrier also orders LDS writes for MFMA reads
    }
}

// ---------------------------------------------------------------------------
// Phase B: 64 blocks: g = blockIdx&3 (batches 16g..), j = blockIdx>>2 (cols 32j..).
// Waves: w0,w1 = z (nt 0/1) then h~ + update; w2,w3 = r (nt 0/1).
// ---------------------------------------------------------------------------
__global__ __launch_bounds__(256)
void gru_recur(const float* __restrict__ Uz, const float* __restrict__ Ur,
               const float* __restrict__ Uh,
               const unsigned short* __restrict__ xp2,  // [g][s][1536][16] bf16
               unsigned long long* __restrict__ hb,     // [2][4][4096] {pair,epoch} h
               unsigned long long* __restrict__ rb,     // [2][4][4096] {pair,epoch} r*h
               float* __restrict__ hgf,                 // fp32 final h [64][512]
               unsigned int* __restrict__ flags,        // end-of-kernel barrier only
               const float* __restrict__ Wf, const float* __restrict__ bfv,
               float* __restrict__ out)
{
    __shared__ unsigned int ldsA32[4096];   // staged h (data halves)
    __shared__ unsigned int ldsB32[4096];   // staged r*h
    __shared__ float hlds[16][33];          // fp32 h for r-waves
    const int tid  = threadIdx.x;
    const int wave = tid >> 6;
    const int lane = tid & 63;
    const int quad = lane >> 4;
    const int l16  = lane & 15;
    const int g  = blockIdx.x & 3;
    const int j  = blockIdx.x >> 2;
    const int b0 = g * 16;
    const int i0 = j * 32;
    const int nt = wave & 1;
    const bool isZ = (wave < 2);

    for (int i = tid; i < 16 * 33; i += 256) (&hlds[0][0])[i] = 0.f;

    // ---- weight B-fragments, stationary in VGPRs ----
    const int wrow = i0 + nt * 16 + l16;
    const int kofs = quad * 8;
    bf16x8 wp1[16], wp2[16];
    const float* U1 = isZ ? Uz : Ur;
#pragma unroll
    for (int kb = 0; kb < 16; ++kb) {
        const float* s1 = U1 + (size_t)wrow * HDIM + kb * 32 + kofs;
        const float* s2 = Uh + (size_t)wrow * HDIM + kb * 32 + kofs;
        bf16x8 w1, w2;
#pragma unroll
        for (int e = 0; e < 8; ++e) {
            w1[e] = (short)f2bf(s1[e]);
            w2[e] = (short)f2bf(s2[e]);
        }
        wp1[kb] = w1; wp2[kb] = w2;
    }

    const int iloc = nt * 16 + l16;
    const int icol = i0 + iloc;
    // producer word64 index base (frag-major pairs): + row*4
    const int wbase = (icol >> 5) * 256 + ((icol >> 3) & 3) * 64 + ((icol & 7) >> 1);
    unsigned long long* hbG = hb + (size_t)g * 4096;          // + par*4*4096
    unsigned long long* rbG = rb + (size_t)g * 4096;
    const unsigned short* xpg = xp2 + (size_t)g * S_LEN * GATES3 * 16;
    const int gofs1 = isZ ? 0 : HDIM;

    float zfrag[4];
    float hm[4] = {0.f, 0.f, 0.f, 0.f};

    // prefetch xp for t=0
    unsigned long long xg_cur = *(const unsigned long long*)
        (xpg + ((size_t)0 * GATES3 + gofs1 + icol) * 16 + quad * 4);
    unsigned long long xh_cur = *(const unsigned long long*)
        (xpg + ((size_t)0 * GATES3 + 2 * HDIM + icol) * 16 + quad * 4);

    __syncthreads();   // hlds init visible

    for (int t = 0; t < S_LEN; ++t) {
        const unsigned int epNew = (unsigned)t + 1u;
        // ---- phase 1: stage h(t-1) from hb[(t+1)&1] expecting epoch t ----
        stage_epoch(hbG + (size_t)(((t + 1) & 1) * 4) * 4096, ldsA32, tid, (unsigned)t);

        f32x4 c1 = {0.f, 0.f, 0.f, 0.f};
#pragma unroll
        for (int kb = 0; kb < 16; ++kb) {
            const bf16x8 a = *(const bf16x8*)((const unsigned short*)ldsA32 + kb * 512 + quad * 128 + l16 * 8);
            c1 = __builtin_amdgcn_mfma_f32_16x16x32_bf16(a, wp1[kb], c1, 0, 0, 0);
        }
        union { unsigned long long q; unsigned short s[4]; } xq;
        xq.q = xg_cur;
        if (isZ) {
#pragma unroll
            for (int r = 0; r < 4; ++r) {
                const float pre = c1[r] + bf2f(xq.s[r]);
                zfrag[r] = 1.f / (1.f + __expf(-pre));
            }
        } else {
            unsigned long long* rbP = rbG + (size_t)((t & 1) * 4) * 4096;
#pragma unroll
            for (int r = 0; r < 4; ++r) {
                const float pre = c1[r] + bf2f(xq.s[r]);
                const float v = 1.f / (1.f + __expf(-pre));
                const float rh = v * hlds[quad * 4 + r][iloc];
                unsigned int my = f2bf(rh);
                unsigned int other = (unsigned int)__shfl_xor((int)my, 1, 64);
                if ((lane & 1) == 0)
                    g_store64(rbP + wbase + (quad * 4 + r) * 4,
                              (unsigned long long)(my | (other << 16)) |
                              ((unsigned long long)epNew << 32));
            }
        }

        // ---- phase 2: stage r*h(t) from rb[t&1] expecting epoch t+1 ----
        stage_epoch(rbG + (size_t)((t & 1) * 4) * 4096, ldsB32, tid, epNew);

        if (isZ) {
            f32x4 c2 = {0.f, 0.f, 0.f, 0.f};
#pragma unroll
            for (int kb = 0; kb < 16; ++kb) {
                const bf16x8 a = *(const bf16x8*)((const unsigned short*)ldsB32 + kb * 512 + quad * 128 + l16 * 8);
                c2 = __builtin_amdgcn_mfma_f32_16x16x32_bf16(a, wp2[kb], c2, 0, 0, 0);
            }
            union { unsigned long long q; unsigned short s[4]; } xh;
            xh.q = xh_cur;
            float hn[4];
#pragma unroll
            for (int r = 0; r < 4; ++r) {
                const float pre = c2[r] + bf2f(xh.s[r]);
                const float ht = tanhf(pre);
                hn[r] = hm[r] + zfrag[r] * (ht - hm[r]);
                hm[r] = hn[r];
            }
            unsigned long long* hbP = hbG + (size_t)((t & 1) * 4) * 4096;
#pragma unroll
            for (int r = 0; r < 4; ++r) {
                unsigned int my = f2bf(hn[r]);
                unsigned int other = (unsigned int)__shfl_xor((int)my, 1, 64);
                if ((lane & 1) == 0)
                    g_store64(hbP + wbase + (quad * 4 + r) * 4,
                              (unsigned long long)(my | (other << 16)) |
                              ((unsigned long long)epNew << 32));
            }
#pragma unroll
            for (int r = 0; r < 4; ++r) {
                hlds[quad * 4 + r][iloc] = hn[r];
                if (t == S_LEN - 1)
                    g_store32(hgf + (size_t)(b0 + quad * 4 + r) * HDIM + icol,
                              __float_as_uint(hn[r]));
            }
        }
        // prefetch xp for t+1 (overlaps producers' store latency / next stage spin)
        const int tn = (t + 1 < S_LEN) ? t + 1 : t;
        xg_cur = *(const unsigned long long*)
            (xpg + ((size_t)tn * GATES3 + gofs1 + icol) * 16 + quad * 4);
        xh_cur = *(const unsigned long long*)
            (xpg + ((size_t)tn * GATES3 + 2 * HDIM + icol) * 16 + quad * 4);
    }

    // ---- one-shot end barrier (hgf visible), then final projection ----
    __syncthreads();                                // drains this block's hgf stores
    if (tid == 0) g_store32(&flags[(g * 16 + j) * 16], 1u);
    if (j == 0) {
        if (lane < 16) {
            const unsigned int* f = &flags[(g * 16 + lane) * 16];
            while (g_load32(f) < 1u)
                __builtin_amdgcn_s_sleep(2);
        }
        __syncthreads();
        if (tid < 16 * ODIM) {
            const int b = b0 + tid / ODIM;
            const int o = tid % ODIM;
            float acc = bfv[o];
            for (int k = 0; k < HDIM; k += 2) {
                union { unsigned long long q; float f[2]; } w;
                w.q = g_load64(hgf + (size_t)b * HDIM + k);
                acc += w.f[0] * Wf[o * HDIM + k] + w.f[1] * Wf[o * HDIM + k + 1];
            }
            out[b * ODIM + o] = acc;
        }
    }
}

// ---------------------------------------------------------------------------
extern "C" void kernel_launch(void* const* d_in, const int* in_sizes, int n_in,
                              void* d_out, int out_size, void* d_ws, size_t ws_size,
                              hipStream_t stream)
{
    const float* x  = (const float*)d_in[0];
    const float* Wz = (const float*)d_in[1];
    const float* bz = (const float*)d_in[2];
    const float* Uz = (const float*)d_in[3];
    const float* cz = (const float*)d_in[4];
    const float* Wr = (const float*)d_in[5];
    const float* br = (const float*)d_in[6];
    const float* Ur = (const float*)d_in[7];
    const float* cr = (const float*)d_in[8];
    const float* Wh = (const float*)d_in[9];
    const float* bh = (const float*)d_in[10];
    const float* Uh = (const float*)d_in[11];
    const float* ch = (const float*)d_in[12];
    const float* Wf = (const float*)d_in[13];
    const float* bf = (const float*)d_in[14];
    float* out = (float*)d_out;

    char* ws = (char*)d_ws;
    const size_t XPB = (size_t)S_LEN * BATCH * GATES3 * sizeof(unsigned short); // 402,653,184 B
    unsigned short*     xp2 = (unsigned short*)ws;
    unsigned long long* hb  = (unsigned long long*)(ws + XPB);            // 262,144 B
    unsigned long long* rb  = (unsigned long long*)(ws + XPB + 262144);   // 262,144 B
    float*              hgf = (float*)(ws + XPB + 524288);                // 131,072 B
    unsigned int*       flg = (unsigned int*)(ws + XPB + 655360);         // 4,096 B

    // zero => h(-1)=0 with epoch 0 in BOTH parities (t=0 expects epoch 0 in hb[1]);
    // rb epochs 0 < 1 => consumers wait for step-0 producers. Re-zeroed every launch.
    hipMemsetAsync(ws + XPB, 0, 524288 + 131072 + 4096, stream);

    proj_mfma<<<dim3(12, 1024), 256, 0, stream>>>(
        x, Wz, Wr, Wh, bz, cz, br, cr, bh, ch, xp2);

    gru_recur<<<dim3(64), dim3(256), 0, stream>>>(
        Uz, Ur, Uh, xp2, hb, rb, hgf, flg, Wf, bf, out);
}